// Round 10
// baseline (19.233 us; speedup 1.0000x reference)
//
#include <hip/hip_runtime.h>
#include <math.h>

#define NBATCH 2048
#define GS 14
#define NCELL (GS * GS)          // 196
#define NCH 30
#define NPRED (NCELL * NCH)      // 5880 floats per batch slab
#define MAXOBJ 20
#define NCLS 20
#define THREADS 256

#define OBJ_BLOCKS 512           // 4 obj-waves per block -> 2048 batches (first in grid)
#define STREAM_BLOCKS 2048       // 8 blocks/CU -> full 32 waves/CU occupancy
#define TOTAL_BLOCKS (OBJ_BLOCKS + STREAM_BLOCKS)

// Conf-quad stream: 2048*5880 floats = 200,704 windows of 60 floats (15 quads,
// spanning 2 cells). Conf quads per window: q mod 15 in {0,1,7,8}; the conf
// float is component m of the quad (m = work-index & 3). Validated in R8.
#define NWIN 200704
#define NWORK (NWIN * 4)                     // 802,816 quad-reads
#define STREAM_THREADS (STREAM_BLOCKS * THREADS)   // 524,288
#define SNITER 2                             // ceil(NWORK / STREAM_THREADS)

typedef float v4f __attribute__((ext_vector_type(4)));

// ws layout: partials[blk*8+k]
//  k: 0=s_sub 1=c_occ 2=s_objconf 3=s_xy 4=s_wh 5=s_clc 6=c_obj1 7=s_all
// (s_noobj = Σ7 − Σ0;  c_noobj = NBATCH*NCELL − Σ1)

__global__ __launch_bounds__(256) void yolo_main_kernel(
        const float* __restrict__ pred,
        const float* __restrict__ target,
        float* __restrict__ ws)
{
    __shared__ float s_red[4][8];
    const int blk = blockIdx.x;
    const int tid = threadIdx.x;
    const int wave = tid >> 6;
    const int lane = tid & 63;
    const float fg = (float)GS;

    float v0 = 0.f, v1 = 0.f, v2 = 0.f, v3 = 0.f, v4 = 0.f, v5 = 0.f, v6 = 0.f;
    float acc = 0.f;

    if (blk >= OBJ_BLOCKS) {
        // ---------------- stream role: sparse conf-quad reads ----------------
        const int gtid = (blk - OBJ_BLOCKS) * THREADS + tid;
        const v4f* g4 = (const v4f*)pred;
        #pragma unroll
        for (int k = 0; k < SNITER; ++k) {
            int w = gtid + k * STREAM_THREADS;
            if (w < NWORK) {
                int m = w & 3;
                int g = w >> 2;
                int q = g * 15 + (m & 1) + ((m >> 1) * 7);  // {0,1,7,8}[m]
                v4f x = g4[q];
                float val = (m == 0) ? x[0] : (m == 1) ? x[1] : (m == 2) ? x[2] : x[3];
                acc += val * val;
            }
        }
    } else {
        // ---------------- object role: one batch per wave ----------------
        const int b = blk * 4 + wave;
        const int o = lane;

        float t0 = 0.f, t1 = 0.f, t2 = 0.f, t3 = 0.f, t4 = 0.f;
        if (lane < MAXOBJ) {
            const float* tb = target + (size_t)b * (MAXOBJ * 5) + lane * 5;
            t0 = tb[0]; t1 = tb[1]; t2 = tb[2]; t3 = tb[3]; t4 = tb[4];
        }

        bool valid = false;
        int cell = 0, mi = 0, cls = 0;
        float offx = 0.f, offy = 0.f, w = 0.f, h = 0.f;
        float pc[10];
        #pragma unroll
        for (int i = 0; i < 10; ++i) pc[i] = 0.f;

        if (o < MAXOBJ && (t0 + t1 + t2 + t3 + t4) != 0.0f) {
            valid = true;
            float cx = (t0 + t2) * 0.5f * fg;
            float cy = (t1 + t3) * 0.5f * fg;
            w = t2 - t0;
            h = t3 - t1;
            int gx = min(max((int)floorf(cx), 0), GS - 1);
            int gy = min(max((int)floorf(cy), 0), GS - 1);
            offx = cx - (float)gx;
            offy = cy - (float)gy;
            cell = gy * GS + gx;
            cls = (int)t4;
            const float2* p2 = (const float2*)(pred + ((size_t)b * NCELL + cell) * NCH);
            #pragma unroll
            for (int i = 0; i < 5; ++i) {
                float2 xx = p2[i];
                pc[2 * i] = xx.x;
                pc[2 * i + 1] = xx.y;
            }
            float tcx = offx / fg, tcy = offy / fg;
            float tlx = tcx - 0.5f * w, tly = tcy - 0.5f * h;
            float trx = tcx + 0.5f * w, trY = tcy + 0.5f * h;
            float ta = (trx - tlx) * (trY - tly);
            float iou0, iou1;
            {
                float px = pc[1] / fg, py = pc[2] / fg;
                float pw = pc[3], ph = pc[4];
                float plx = px - 0.5f * pw, ply = py - 0.5f * ph;
                float prx = px + 0.5f * pw, prY = py + 0.5f * ph;
                float ix = fmaxf(fminf(prx, trx) - fmaxf(plx, tlx), 0.f);
                float iy = fmaxf(fminf(prY, trY) - fmaxf(ply, tly), 0.f);
                float inter = ix * iy;
                float a1 = (prx - plx) * (prY - ply);
                iou0 = inter / (a1 + ta - inter);
            }
            {
                float px = pc[6] / fg, py = pc[7] / fg;
                float pw = pc[8], ph = pc[9];
                float plx = px - 0.5f * pw, ply = py - 0.5f * ph;
                float prx = px + 0.5f * pw, prY = py + 0.5f * ph;
                float ix = fmaxf(fminf(prx, trx) - fmaxf(plx, tlx), 0.f);
                float iy = fmaxf(fminf(prY, trY) - fmaxf(ply, tly), 0.f);
                float inter = ix * iy;
                float a1 = (prx - plx) * (prY - ply);
                iou1 = inter / (a1 + ta - inter);
            }
            mi = (iou1 > iou0) ? 1 : 0;      // argmax, first-wins on tie
        }

        // packed key: cell | mi<<8 | cls<<16 (per-wave ballots/shuffles)
        int pack = cell | (mi << 8) | (cls << 16);
        unsigned long long vm = __ballot(valid);

        bool win = valid;
        #pragma unroll
        for (int j = 0; j < MAXOBJ; ++j) {
            int pj = __shfl(pack, j);
            if (((vm >> j) & 1ull) && j > o && (pj & 0x1FF) == (pack & 0x1FF))
                win = false;
        }
        unsigned long long wmask = __ballot(win);

        bool other = false;
        bool rep = win;
        unsigned int clsmask = 0u;
        #pragma unroll
        for (int j = 0; j < MAXOBJ; ++j) {
            int pj = __shfl(pack, j);
            int cj = pj & 0xFF;
            int mj = (pj >> 8) & 1;
            int clj = (pj >> 16) & 0xFF;
            bool vj = (vm >> j) & 1ull;
            bool wj = (wmask >> j) & 1ull;
            if (wj && cj == cell && mj != mi) other = true;
            if (wj && j < o && cj == cell) rep = false;
            if (vj && cj == cell) clsmask |= (1u << clj);
        }

        if (rep) {                               // once per occupied cell
            v0 = pc[0] * pc[0] + pc[5] * pc[5];  // s_sub
            v1 = 1.0f;                           // c_occ
        }
        if (win && !other) {                     // nset==1 responsible box
            float conf = mi ? pc[5] : pc[0];
            float px   = mi ? pc[6] : pc[1];
            float py   = mi ? pc[7] : pc[2];
            float pw   = mi ? pc[8] : pc[3];
            float ph   = mi ? pc[9] : pc[4];
            float dconf = conf - 1.0f;
            v2 = dconf * dconf;
            float dx = px - offx, dy = py - offy;
            v3 = dx * dx + dy * dy;
            float sw = sqrtf(pw) - sqrtf(w);
            float sh = sqrtf(ph) - sqrtf(h);
            v4 = sw * sw + sh * sh;
            const float2* p2 = (const float2*)(pred + ((size_t)b * NCELL + cell) * NCH);
            float clc = 0.f;
            #pragma unroll
            for (int k = 0; k < 10; ++k) {
                float2 xx = p2[5 + k];
                float c0 = ((clsmask >> (2 * k)) & 1u) ? 1.0f : 0.0f;
                float c1 = ((clsmask >> (2 * k + 1)) & 1u) ? 1.0f : 0.0f;
                float d0 = xx.x - c0, d1 = xx.y - c1;
                clc += d0 * d0 + d1 * d1;
            }
            v5 = clc;
            v6 = 1.0f;                           // c_obj1
        }

        #pragma unroll
        for (int off = 32; off > 0; off >>= 1) {
            v0 += __shfl_down(v0, off);
            v1 += __shfl_down(v1, off);
            v2 += __shfl_down(v2, off);
            v3 += __shfl_down(v3, off);
            v4 += __shfl_down(v4, off);
            v5 += __shfl_down(v5, off);
            v6 += __shfl_down(v6, off);
        }
    }

    // ---- per-wave stream-sum reduce, cross-wave combine via LDS ----
    #pragma unroll
    for (int off = 32; off > 0; off >>= 1) acc += __shfl_down(acc, off);

    if (lane == 0) {
        s_red[wave][0] = v0; s_red[wave][1] = v1; s_red[wave][2] = v2;
        s_red[wave][3] = v3; s_red[wave][4] = v4; s_red[wave][5] = v5;
        s_red[wave][6] = v6; s_red[wave][7] = acc;
    }
    __syncthreads();
    if (tid == 0) {
        float* p = ws + (size_t)blk * 8;
        #pragma unroll
        for (int k = 0; k < 8; ++k)
            p[k] = s_red[0][k] + s_red[1][k] + s_red[2][k] + s_red[3][k];
    }
}

// ---------------------------------------------------------------------------
// Final kernel: deterministic fixed-order reduction of 2560 rows + formula.
// ---------------------------------------------------------------------------
__global__ __launch_bounds__(256) void yolo_final_kernel(
        const float* __restrict__ ws,
        float* __restrict__ out)
{
    __shared__ float s_red[4][8];
    const int tid = threadIdx.x;
    const int wave = tid >> 6;
    const int lane = tid & 63;

    float v[8] = {0.f, 0.f, 0.f, 0.f, 0.f, 0.f, 0.f, 0.f};
    for (int r = tid; r < TOTAL_BLOCKS; r += THREADS) {
        const float4* p = (const float4*)(ws + (size_t)r * 8);
        float4 x0 = p[0];
        float4 x1 = p[1];
        v[0] += x0.x; v[1] += x0.y; v[2] += x0.z; v[3] += x0.w;
        v[4] += x1.x; v[5] += x1.y; v[6] += x1.z; v[7] += x1.w;
    }
    #pragma unroll
    for (int off = 32; off > 0; off >>= 1) {
        #pragma unroll
        for (int k = 0; k < 8; ++k) v[k] += __shfl_down(v[k], off);
    }
    if (lane == 0) {
        #pragma unroll
        for (int k = 0; k < 8; ++k) s_red[wave][k] = v[k];
    }
    __syncthreads();
    if (tid == 0) {
        float s_sub     = s_red[0][0] + s_red[1][0] + s_red[2][0] + s_red[3][0];
        float c_occ     = s_red[0][1] + s_red[1][1] + s_red[2][1] + s_red[3][1];
        float s_objconf = s_red[0][2] + s_red[1][2] + s_red[2][2] + s_red[3][2];
        float s_xy      = s_red[0][3] + s_red[1][3] + s_red[2][3] + s_red[3][3];
        float s_wh      = s_red[0][4] + s_red[1][4] + s_red[2][4] + s_red[3][4];
        float s_clc     = s_red[0][5] + s_red[1][5] + s_red[2][5] + s_red[3][5];
        float c_obj1    = s_red[0][6] + s_red[1][6] + s_red[2][6] + s_red[3][6];
        float s_all     = s_red[0][7] + s_red[1][7] + s_red[2][7] + s_red[3][7];

        float s_noobj = s_all - s_sub;
        float c_noobj = (float)(NBATCH * NCELL) - c_occ;
        float n_noobj = 2.0f * c_noobj;
        float n_resp  = c_obj1;
        float noobj_loss   = s_noobj / n_noobj;
        float objconf_loss = s_objconf / n_resp;
        float loss_xy  = s_xy / (n_resp * 2.0f);
        float loss_wh  = s_wh / (n_resp * 2.0f);
        float loss_clc = s_clc / (c_obj1 * (float)NCLS);
        out[0] = 5.0f * (loss_xy + loss_wh) + objconf_loss
               + 0.5f * noobj_loss + loss_clc;
    }
}

extern "C" void kernel_launch(void* const* d_in, const int* in_sizes, int n_in,
                              void* d_out, int out_size, void* d_ws, size_t ws_size,
                              hipStream_t stream) {
    const float* pred = (const float*)d_in[0];
    const float* target = (const float*)d_in[1];
    float* ws = (float*)d_ws;     // 2560*8 floats = 80 KiB, fully overwritten
    float* out = (float*)d_out;

    yolo_main_kernel<<<TOTAL_BLOCKS, THREADS, 0, stream>>>(pred, target, ws);
    yolo_final_kernel<<<1, THREADS, 0, stream>>>(ws, out);
}

// Round 11
// 15.849 us; speedup vs baseline: 1.2135x; 1.2135x over previous
//
#include <hip/hip_runtime.h>
#include <math.h>

#define NBATCH 2048
#define GS 14
#define NCELL (GS * GS)          // 196
#define NCH 30
#define NPRED (NCELL * NCH)      // 5880 floats per batch slab
#define MAXOBJ 20
#define NCLS 20
#define THREADS 256

#define OBJ_BLOCKS 512           // blocks 0..511: obj-only (4 waves -> 4 batches each)
#define STREAM_BLOCKS 512        // blocks 512..1023: stream-only, depth-7 NT sparse
#define TOTAL_BLOCKS (OBJ_BLOCKS + STREAM_BLOCKS)

// Conf-quad stream (validated R8): 12,042,240 floats = 200,704 windows of 60
// floats (15 quads). Conf quads: q mod 15 in {0,1,7,8}; conf float = component
// m of the quad (m = work-index & 3).
#define NWIN 200704
#define NWORK (NWIN * 4)                         // 802,816 quad-reads
#define STREAM_THREADS (STREAM_BLOCKS * THREADS) // 131,072
#define SNITER 7                                 // ceil(NWORK / STREAM_THREADS)

typedef float v4f __attribute__((ext_vector_type(4)));

// ws layout: partials[blk*8+k]
//  k: 0=s_sub 1=c_occ 2=s_objconf 3=s_xy 4=s_wh 5=s_clc 6=c_obj1 7=s_all
// (s_noobj = Σ7 − Σ0;  c_noobj = NBATCH*NCELL − Σ1)

__global__ __launch_bounds__(256) void yolo_main_kernel(
        const float* __restrict__ pred,
        const float* __restrict__ target,
        float* __restrict__ ws)
{
    __shared__ float s_red[4][8];
    const int blk = blockIdx.x;
    const int tid = threadIdx.x;
    const int wave = tid >> 6;
    const int lane = tid & 63;
    const float fg = (float)GS;

    float v0 = 0.f, v1 = 0.f, v2 = 0.f, v3 = 0.f, v4 = 0.f, v5 = 0.f, v6 = 0.f;
    float acc = 0.f;

    if (blk >= OBJ_BLOCKS) {
        // ------------- stream role: depth-7 NT sparse conf-quad reads -------------
        const int gtid = (blk - OBJ_BLOCKS) * THREADS + tid;
        const v4f* g4 = (const v4f*)pred;

        v4f xr[SNITER];
        int wm_[SNITER];
        #pragma unroll
        for (int k = 0; k < SNITER; ++k) {
            int w = gtid + k * STREAM_THREADS;
            int wc = (w < NWORK) ? w : (NWORK - 1);   // clamp addr, mask later
            int m = wc & 3;
            int g = wc >> 2;
            int q = g * 15 + (m & 1) + ((m >> 1) * 7);  // {0,1,7,8}[m]
            wm_[k] = (w < NWORK) ? m : -1;
            xr[k] = __builtin_nontemporal_load(&g4[q]);
        }
        #pragma unroll
        for (int k = 0; k < SNITER; ++k) {
            int m = wm_[k];
            if (m >= 0) {
                v4f x = xr[k];
                float val = (m == 0) ? x[0] : (m == 1) ? x[1] : (m == 2) ? x[2] : x[3];
                acc += val * val;
            }
        }
    } else {
        // ------------- object role: one batch per wave (validated) -------------
        const int b = blk * 4 + wave;
        const int o = lane;

        float t0 = 0.f, t1 = 0.f, t2 = 0.f, t3 = 0.f, t4 = 0.f;
        if (lane < MAXOBJ) {
            const float* tb = target + (size_t)b * (MAXOBJ * 5) + lane * 5;
            t0 = tb[0]; t1 = tb[1]; t2 = tb[2]; t3 = tb[3]; t4 = tb[4];
        }

        bool valid = false;
        int cell = 0, mi = 0, cls = 0;
        float offx = 0.f, offy = 0.f, w = 0.f, h = 0.f;
        float pc[10];
        #pragma unroll
        for (int i = 0; i < 10; ++i) pc[i] = 0.f;

        if (o < MAXOBJ && (t0 + t1 + t2 + t3 + t4) != 0.0f) {
            valid = true;
            float cx = (t0 + t2) * 0.5f * fg;
            float cy = (t1 + t3) * 0.5f * fg;
            w = t2 - t0;
            h = t3 - t1;
            int gx = min(max((int)floorf(cx), 0), GS - 1);
            int gy = min(max((int)floorf(cy), 0), GS - 1);
            offx = cx - (float)gx;
            offy = cy - (float)gy;
            cell = gy * GS + gx;
            cls = (int)t4;
            const float2* p2 = (const float2*)(pred + ((size_t)b * NCELL + cell) * NCH);
            #pragma unroll
            for (int i = 0; i < 5; ++i) {
                float2 xx = p2[i];
                pc[2 * i] = xx.x;
                pc[2 * i + 1] = xx.y;
            }
            float tcx = offx / fg, tcy = offy / fg;
            float tlx = tcx - 0.5f * w, tly = tcy - 0.5f * h;
            float trx = tcx + 0.5f * w, trY = tcy + 0.5f * h;
            float ta = (trx - tlx) * (trY - tly);
            float iou0, iou1;
            {
                float px = pc[1] / fg, py = pc[2] / fg;
                float pw = pc[3], ph = pc[4];
                float plx = px - 0.5f * pw, ply = py - 0.5f * ph;
                float prx = px + 0.5f * pw, prY = py + 0.5f * ph;
                float ix = fmaxf(fminf(prx, trx) - fmaxf(plx, tlx), 0.f);
                float iy = fmaxf(fminf(prY, trY) - fmaxf(ply, tly), 0.f);
                float inter = ix * iy;
                float a1 = (prx - plx) * (prY - ply);
                iou0 = inter / (a1 + ta - inter);
            }
            {
                float px = pc[6] / fg, py = pc[7] / fg;
                float pw = pc[8], ph = pc[9];
                float plx = px - 0.5f * pw, ply = py - 0.5f * ph;
                float prx = px + 0.5f * pw, prY = py + 0.5f * ph;
                float ix = fmaxf(fminf(prx, trx) - fmaxf(plx, tlx), 0.f);
                float iy = fmaxf(fminf(prY, trY) - fmaxf(ply, tly), 0.f);
                float inter = ix * iy;
                float a1 = (prx - plx) * (prY - ply);
                iou1 = inter / (a1 + ta - inter);
            }
            mi = (iou1 > iou0) ? 1 : 0;      // argmax, first-wins on tie
        }

        int pack = cell | (mi << 8) | (cls << 16);
        unsigned long long vm = __ballot(valid);

        bool win = valid;
        #pragma unroll
        for (int j = 0; j < MAXOBJ; ++j) {
            int pj = __shfl(pack, j);
            if (((vm >> j) & 1ull) && j > o && (pj & 0x1FF) == (pack & 0x1FF))
                win = false;
        }
        unsigned long long wmask = __ballot(win);

        bool other = false;
        bool rep = win;
        unsigned int clsmask = 0u;
        #pragma unroll
        for (int j = 0; j < MAXOBJ; ++j) {
            int pj = __shfl(pack, j);
            int cj = pj & 0xFF;
            int mj = (pj >> 8) & 1;
            int clj = (pj >> 16) & 0xFF;
            bool vj = (vm >> j) & 1ull;
            bool wj = (wmask >> j) & 1ull;
            if (wj && cj == cell && mj != mi) other = true;
            if (wj && j < o && cj == cell) rep = false;
            if (vj && cj == cell) clsmask |= (1u << clj);
        }

        if (rep) {                               // once per occupied cell
            v0 = pc[0] * pc[0] + pc[5] * pc[5];  // s_sub
            v1 = 1.0f;                           // c_occ
        }
        if (win && !other) {                     // nset==1 responsible box
            float conf = mi ? pc[5] : pc[0];
            float px   = mi ? pc[6] : pc[1];
            float py   = mi ? pc[7] : pc[2];
            float pw   = mi ? pc[8] : pc[3];
            float ph   = mi ? pc[9] : pc[4];
            float dconf = conf - 1.0f;
            v2 = dconf * dconf;
            float dx = px - offx, dy = py - offy;
            v3 = dx * dx + dy * dy;
            float sw = sqrtf(pw) - sqrtf(w);
            float sh = sqrtf(ph) - sqrtf(h);
            v4 = sw * sw + sh * sh;
            const float2* p2 = (const float2*)(pred + ((size_t)b * NCELL + cell) * NCH);
            float clc = 0.f;
            #pragma unroll
            for (int k = 0; k < 10; ++k) {
                float2 xx = p2[5 + k];
                float c0 = ((clsmask >> (2 * k)) & 1u) ? 1.0f : 0.0f;
                float c1 = ((clsmask >> (2 * k + 1)) & 1u) ? 1.0f : 0.0f;
                float d0 = xx.x - c0, d1 = xx.y - c1;
                clc += d0 * d0 + d1 * d1;
            }
            v5 = clc;
            v6 = 1.0f;                           // c_obj1
        }

        #pragma unroll
        for (int off = 32; off > 0; off >>= 1) {
            v0 += __shfl_down(v0, off);
            v1 += __shfl_down(v1, off);
            v2 += __shfl_down(v2, off);
            v3 += __shfl_down(v3, off);
            v4 += __shfl_down(v4, off);
            v5 += __shfl_down(v5, off);
            v6 += __shfl_down(v6, off);
        }
    }

    // ---- per-wave stream-sum reduce, cross-wave combine via LDS ----
    #pragma unroll
    for (int off = 32; off > 0; off >>= 1) acc += __shfl_down(acc, off);

    if (lane == 0) {
        s_red[wave][0] = v0; s_red[wave][1] = v1; s_red[wave][2] = v2;
        s_red[wave][3] = v3; s_red[wave][4] = v4; s_red[wave][5] = v5;
        s_red[wave][6] = v6; s_red[wave][7] = acc;
    }
    __syncthreads();
    if (tid == 0) {
        float* p = ws + (size_t)blk * 8;
        #pragma unroll
        for (int k = 0; k < 8; ++k)
            p[k] = s_red[0][k] + s_red[1][k] + s_red[2][k] + s_red[3][k];
    }
}

// ---------------------------------------------------------------------------
// Final kernel: deterministic fixed-order reduction of 1024 rows + formula.
// ---------------------------------------------------------------------------
__global__ __launch_bounds__(256) void yolo_final_kernel(
        const float* __restrict__ ws,
        float* __restrict__ out)
{
    __shared__ float s_red[4][8];
    const int tid = threadIdx.x;
    const int wave = tid >> 6;
    const int lane = tid & 63;

    float v[8] = {0.f, 0.f, 0.f, 0.f, 0.f, 0.f, 0.f, 0.f};
    for (int r = tid; r < TOTAL_BLOCKS; r += THREADS) {
        const float4* p = (const float4*)(ws + (size_t)r * 8);
        float4 x0 = p[0];
        float4 x1 = p[1];
        v[0] += x0.x; v[1] += x0.y; v[2] += x0.z; v[3] += x0.w;
        v[4] += x1.x; v[5] += x1.y; v[6] += x1.z; v[7] += x1.w;
    }
    #pragma unroll
    for (int off = 32; off > 0; off >>= 1) {
        #pragma unroll
        for (int k = 0; k < 8; ++k) v[k] += __shfl_down(v[k], off);
    }
    if (lane == 0) {
        #pragma unroll
        for (int k = 0; k < 8; ++k) s_red[wave][k] = v[k];
    }
    __syncthreads();
    if (tid == 0) {
        float s_sub     = s_red[0][0] + s_red[1][0] + s_red[2][0] + s_red[3][0];
        float c_occ     = s_red[0][1] + s_red[1][1] + s_red[2][1] + s_red[3][1];
        float s_objconf = s_red[0][2] + s_red[1][2] + s_red[2][2] + s_red[3][2];
        float s_xy      = s_red[0][3] + s_red[1][3] + s_red[2][3] + s_red[3][3];
        float s_wh      = s_red[0][4] + s_red[1][4] + s_red[2][4] + s_red[3][4];
        float s_clc     = s_red[0][5] + s_red[1][5] + s_red[2][5] + s_red[3][5];
        float c_obj1    = s_red[0][6] + s_red[1][6] + s_red[2][6] + s_red[3][6];
        float s_all     = s_red[0][7] + s_red[1][7] + s_red[2][7] + s_red[3][7];

        float s_noobj = s_all - s_sub;
        float c_noobj = (float)(NBATCH * NCELL) - c_occ;
        float n_noobj = 2.0f * c_noobj;
        float n_resp  = c_obj1;
        float noobj_loss   = s_noobj / n_noobj;
        float objconf_loss = s_objconf / n_resp;
        float loss_xy  = s_xy / (n_resp * 2.0f);
        float loss_wh  = s_wh / (n_resp * 2.0f);
        float loss_clc = s_clc / (c_obj1 * (float)NCLS);
        out[0] = 5.0f * (loss_xy + loss_wh) + objconf_loss
               + 0.5f * noobj_loss + loss_clc;
    }
}

extern "C" void kernel_launch(void* const* d_in, const int* in_sizes, int n_in,
                              void* d_out, int out_size, void* d_ws, size_t ws_size,
                              hipStream_t stream) {
    const float* pred = (const float*)d_in[0];
    const float* target = (const float*)d_in[1];
    float* ws = (float*)d_ws;     // 1024*8 floats = 32 KiB, fully overwritten
    float* out = (float*)d_out;

    yolo_main_kernel<<<TOTAL_BLOCKS, THREADS, 0, stream>>>(pred, target, ws);
    yolo_final_kernel<<<1, THREADS, 0, stream>>>(ws, out);
}